// Round 1
// baseline (1702.394 us; speedup 1.0000x reference)
//
#include <hip/hip_runtime.h>

#define T_TOTAL 65536
#define NLAYERS 20
#define OUT_START 2047
#define OUT_W 63489
#define COUT 256

// workspace layout in floats
#define WPACK_PER_LAYER 24576               // WF(128x64) WG(128x64) WR(64x64) WS(64x64)
#define W0T_OFF (NLAYERS * WPACK_PER_LAYER) // 491520
#define W1T_OFF (W0T_OFF + 4096)            // 495616
#define PACK_TOTAL (W1T_OFF + 16384)        // 512000
#define H0_OFF 524288
#define HBUF_FLOATS (64 * T_TOTAL)          // 4194304
#define H1_OFF (H0_OFF + HBUF_FLOATS)
#define SKIP_OFF (H0_OFF + 2 * HBUF_FLOATS)

// ---------------------------------------------------------------- pack weights
// Transposed layouts so per-wave weight reads are along contiguous o at fixed k.
__global__ __launch_bounds__(256) void pack_weights(
    const float* __restrict__ wf, const float* __restrict__ wg,
    const float* __restrict__ wr, const float* __restrict__ wsk,
    const float* __restrict__ w0, const float* __restrict__ w1,
    float* __restrict__ wp)
{
    int idx = blockIdx.x * 256 + threadIdx.x;
    if (idx >= PACK_TOTAL) return;
    float v;
    if (idx < W0T_OFF) {
        int i = idx / WPACK_PER_LAYER;
        int r = idx - i * WPACK_PER_LAYER;
        if (r < 16384) {                      // WF_t / WG_t : [k 0..127][o 0..63]
            const float* src = (r < 8192) ? wf : wg;
            int rr = r & 8191;
            int k = rr >> 6, o = rr & 63;
            v = src[(((i * 64 + o) * 64 + (k & 63)) << 1) + (k >> 6)];
        } else if (r < 20480) {               // WR_t : [c][o]
            int rr = r - 16384; int c = rr >> 6, o = rr & 63;
            v = wr[(i * 64 + o) * 64 + c];
        } else {                              // WS_t : [c][s]
            int rr = r - 20480; int c = rr >> 6, o = rr & 63;
            v = wsk[(i * 64 + o) * 64 + c];
        }
    } else if (idx < W1T_OFF) {               // W0_t : [c][o] 64x64
        int rr = idx - W0T_OFF; int c = rr >> 6, o = rr & 63;
        v = w0[o * 64 + c];
    } else {                                  // W1_t : [c][o] 64x256
        int rr = idx - W1T_OFF; int c = rr >> 8, o = rr & 255;
        v = w1[o * 64 + c];
    }
    wp[idx] = v;
}

// ---------------------------------------------------------------- init h0
__global__ __launch_bounds__(256) void init_h(
    const float* __restrict__ in, const float* __restrict__ w0,
    const float* __restrict__ b0, float* __restrict__ H)
{
    int idx = blockIdx.x * 256 + threadIdx.x;      // exactly 64*65536 threads
    int c = idx >> 16, t = idx & 65535;
    H[idx] = fmaf(w0[c], in[t], b0[c]);
}

// ---------------------------------------------------------------- one layer
__global__ __launch_bounds__(256) void layer_kernel(
    const float* __restrict__ Hin, float* __restrict__ Hout,
    float* __restrict__ skip, const float* __restrict__ WL,
    const float* __restrict__ bf, const float* __restrict__ bg,
    const float* __restrict__ br, const float* __restrict__ bs,
    int d, int tau_start, int accumulate)
{
    __shared__ float Xl[64][64];
    __shared__ float Xr[64][64];
    __shared__ float Z[64][64];
    const int tid = threadIdx.x;
    const int col = tid & 63;
    const int row0 = __builtin_amdgcn_readfirstlane((tid >> 6) << 4);
    const int tau0 = tau_start + (int)blockIdx.x * 64;

    for (int idx = tid; idx < 4096; idx += 256) {
        int c = idx >> 6, cc = idx & 63;
        int tau = tau0 + cc;
        if (tau >= T_TOTAL) tau = T_TOTAL - 1;
        Xr[c][cc] = Hin[c * T_TOTAL + tau];
        Xl[c][cc] = Hin[c * T_TOTAL + tau - d];
    }
    __syncthreads();

    const float* __restrict__ WF = WL;
    const float* __restrict__ WG = WL + 8192;

    float accf[16], accg[16];
    #pragma unroll
    for (int r = 0; r < 16; ++r) { accf[r] = bf[row0 + r]; accg[r] = bg[row0 + r]; }

    #pragma unroll 2
    for (int k = 0; k < 64; ++k) {
        float x = Xl[k][col];
        const float* __restrict__ wfp = WF + k * 64 + row0;
        const float* __restrict__ wgp = WG + k * 64 + row0;
        #pragma unroll
        for (int r = 0; r < 16; ++r) {
            accf[r] = fmaf(wfp[r], x, accf[r]);
            accg[r] = fmaf(wgp[r], x, accg[r]);
        }
    }
    #pragma unroll 2
    for (int k = 0; k < 64; ++k) {
        float x = Xr[k][col];
        const float* __restrict__ wfp = WF + (64 + k) * 64 + row0;
        const float* __restrict__ wgp = WG + (64 + k) * 64 + row0;
        #pragma unroll
        for (int r = 0; r < 16; ++r) {
            accf[r] = fmaf(wfp[r], x, accf[r]);
            accg[r] = fmaf(wgp[r], x, accg[r]);
        }
    }
    #pragma unroll
    for (int r = 0; r < 16; ++r) {
        float e2 = __expf(2.0f * accf[r]);
        float th = 1.0f - 2.0f / (e2 + 1.0f);       // tanh, overflow-safe
        float sg = 1.0f / (1.0f + __expf(-accg[r]));
        Z[row0 + r][col] = th * sg;
    }
    __syncthreads();

    const float* __restrict__ WR = WL + 16384;
    const float* __restrict__ WS = WL + 20480;
    float accr[16], accs[16];
    #pragma unroll
    for (int r = 0; r < 16; ++r) { accr[r] = br[row0 + r]; accs[r] = bs[row0 + r]; }
    #pragma unroll 2
    for (int c = 0; c < 64; ++c) {
        float zv = Z[c][col];
        const float* __restrict__ wrp = WR + c * 64 + row0;
        const float* __restrict__ wsp = WS + c * 64 + row0;
        #pragma unroll
        for (int r = 0; r < 16; ++r) {
            accr[r] = fmaf(wrp[r], zv, accr[r]);
            accs[r] = fmaf(wsp[r], zv, accs[r]);
        }
    }
    int tau = tau0 + col;
    if (tau < T_TOTAL) {
        #pragma unroll
        for (int r = 0; r < 16; ++r)
            Hout[(row0 + r) * T_TOTAL + tau] = accr[r] + Xr[row0 + r][col];
        if (tau >= OUT_START) {
            if (accumulate) {
                #pragma unroll
                for (int r = 0; r < 16; ++r) skip[(row0 + r) * T_TOTAL + tau] += accs[r];
            } else {
                #pragma unroll
                for (int r = 0; r < 16; ++r) skip[(row0 + r) * T_TOTAL + tau] = accs[r];
            }
        }
    }
}

// ---------------------------------------------------------------- output head
__global__ __launch_bounds__(256) void out_kernel(
    const float* __restrict__ skip, const float* __restrict__ alpha,
    const float* __restrict__ W0t, const float* __restrict__ b0,
    const float* __restrict__ W1t, const float* __restrict__ b1,
    float* __restrict__ out)
{
    __shared__ float Y0[64][64];
    __shared__ float Y1[64][64];
    const int tid = threadIdx.x;
    const int col = tid & 63;
    const int row0 = __builtin_amdgcn_readfirstlane((tid >> 6) << 4);
    const int u0 = (int)blockIdx.x * 64;

    for (int idx = tid; idx < 4096; idx += 256) {
        int c = idx >> 6, cc = idx & 63;
        int u = u0 + cc;
        float v = 0.0f;
        if (u < OUT_W) {
            v = skip[c * T_TOTAL + OUT_START + u];
            float a = alpha[c];                    // alpha[0][c]
            v = v > 0.0f ? v : a * v;
        }
        Y0[c][cc] = v;
    }
    __syncthreads();

    {
        float acc[16];
        #pragma unroll
        for (int r = 0; r < 16; ++r) acc[r] = b0[row0 + r];
        #pragma unroll 2
        for (int c = 0; c < 64; ++c) {
            float x = Y0[c][col];
            const float* __restrict__ wp = W0t + c * 64 + row0;
            #pragma unroll
            for (int r = 0; r < 16; ++r) acc[r] = fmaf(wp[r], x, acc[r]);
        }
        #pragma unroll
        for (int r = 0; r < 16; ++r) {
            float a = alpha[64 + row0 + r];        // alpha[1][s]
            float v = acc[r];
            Y1[row0 + r][col] = v > 0.0f ? v : a * v;
        }
    }
    __syncthreads();

    int u = u0 + col;
    #pragma unroll
    for (int p = 0; p < 4; ++p) {
        int o0 = row0 * 4 + p * 16;                // uniform: rg*64 + p*16
        float acc[16];
        #pragma unroll
        for (int r = 0; r < 16; ++r) acc[r] = b1[o0 + r];
        #pragma unroll 2
        for (int c = 0; c < 64; ++c) {
            float x = Y1[c][col];
            const float* __restrict__ wp = W1t + c * 256 + o0;
            #pragma unroll
            for (int r = 0; r < 16; ++r) acc[r] = fmaf(wp[r], x, acc[r]);
        }
        if (u < OUT_W) {
            #pragma unroll
            for (int r = 0; r < 16; ++r) out[(o0 + r) * OUT_W + u] = acc[r];
        }
    }
}

// ---------------------------------------------------------------- launch
extern "C" void kernel_launch(void* const* d_in, const int* in_sizes, int n_in,
                              void* d_out, int out_size, void* d_ws, size_t ws_size,
                              hipStream_t stream)
{
    const float* input  = (const float*)d_in[0];
    const float* w0     = (const float*)d_in[1];
    const float* b0     = (const float*)d_in[2];
    const float* wf     = (const float*)d_in[3];
    const float* bf     = (const float*)d_in[4];
    const float* wg     = (const float*)d_in[5];
    const float* bg     = (const float*)d_in[6];
    const float* wr     = (const float*)d_in[7];
    const float* br     = (const float*)d_in[8];
    const float* wsk    = (const float*)d_in[9];
    const float* bs     = (const float*)d_in[10];
    const float* alpha  = (const float*)d_in[11];
    const float* w_out0 = (const float*)d_in[12];
    const float* b_out0 = (const float*)d_in[13];
    const float* w_out1 = (const float*)d_in[14];
    const float* b_out1 = (const float*)d_in[15];
    float* out = (float*)d_out;

    float* wsbase = (float*)d_ws;
    float* wp   = wsbase;
    float* W0t  = wsbase + W0T_OFF;
    float* W1t  = wsbase + W1T_OFF;
    float* H[2] = { wsbase + H0_OFF, wsbase + H1_OFF };
    float* skip = wsbase + SKIP_OFF;

    pack_weights<<<(PACK_TOTAL + 255) / 256, 256, 0, stream>>>(wf, wg, wr, wsk, w_out0, w_out1, wp);
    init_h<<<(64 * T_TOTAL) / 256, 256, 0, stream>>>(input, w0, b0, H[0]);

    int C = 0;
    for (int i = 0; i < NLAYERS; ++i) {
        int d = 1 << (i % 10);
        C += d;
        int ncols = T_TOTAL - C;
        int nblk = (ncols + 63) / 64;
        layer_kernel<<<nblk, 256, 0, stream>>>(
            H[i & 1], H[(i + 1) & 1], skip, wp + i * WPACK_PER_LAYER,
            bf + i * 64, bg + i * 64, br + i * 64, bs + i * 64,
            d, C, i > 0 ? 1 : 0);
    }

    out_kernel<<<(OUT_W + 63) / 64, 256, 0, stream>>>(skip, alpha, W0t, b_out0, W1t, b_out1, out);
}

// Round 3
// 1090.656 us; speedup vs baseline: 1.5609x; 1.5609x over previous
//
#include <hip/hip_runtime.h>

typedef unsigned short ushort_t;
typedef __attribute__((ext_vector_type(8))) __bf16 bf16x8;
typedef __attribute__((ext_vector_type(4))) float f32x4;
typedef __attribute__((ext_vector_type(4))) unsigned int uint4v;

#define T_TOTAL 65536
#define NLAYERS 20
#define OUT_START 2047
#define OUT_W 63489

// workspace layout
#define W0T_OFF 0                       // 4096 floats
#define W1T_OFF 4096                    // 16384 floats
#define PACKF_TOTAL 20480               // fp32 out-head packs
#define PBF_OFF_FLOATS 20480            // bf16 MFMA packs start (as ushort*)
#define PBF_PER_LAYER 24576             // ushorts: 16384 gates + 8192 rs
#define PBF_TOTAL (NLAYERS * PBF_PER_LAYER)
#define H0_OFF 524288
#define HBUF (64 * T_TOTAL)
#define H1_OFF (H0_OFF + HBUF)
#define SKIP_OFF (H0_OFF + 2 * HBUF)

__device__ __forceinline__ ushort_t f2bf(float x) {
    union { float f; unsigned u; } c; c.f = x;
    unsigned u = c.u + 0x7FFFu + ((c.u >> 16) & 1u);   // RNE
    return (ushort_t)(u >> 16);
}

union BF8 { unsigned long long q[2]; uint4v u4; bf16x8 v; };

// ---------------------------------------------------------------- pack out-head (fp32, transposed)
__global__ __launch_bounds__(256) void pack_out(
    const float* __restrict__ w0, const float* __restrict__ w1, float* __restrict__ wp)
{
    int idx = blockIdx.x * 256 + threadIdx.x;
    if (idx >= PACKF_TOTAL) return;
    if (idx < W1T_OFF) {                  // W0t [c][o] 64x64
        int c = idx >> 6, o = idx & 63;
        wp[W0T_OFF + idx] = w0[o * 64 + c];
    } else {                              // W1t [c][o] 64x256
        int rr = idx - W1T_OFF; int c = rr >> 8, o = rr & 255;
        wp[W1T_OFF + rr] = w1[o * 64 + c];
    }
}

// ---------------------------------------------------------------- pack MFMA weights (bf16, fragment order)
// Gates A (128x128 = [f;g] x [left||right]): PG[mt][ks][lane][j]
//   element = W[mt*16+(l&15)][ks*32+(l>>4)*8+j]
// RS A (128x64 = [r;s] x c): PRS[mt][ks][lane][j], ks<2
__global__ __launch_bounds__(256) void pack_mfma(
    const float* __restrict__ wf, const float* __restrict__ wg,
    const float* __restrict__ wr, const float* __restrict__ wsk,
    ushort_t* __restrict__ out)
{
    int idx = blockIdx.x * 256 + threadIdx.x;
    if (idx >= PBF_TOTAL) return;
    int i = idx / PBF_PER_LAYER;
    int r = idx - i * PBF_PER_LAYER;
    float v;
    if (r < 16384) {                      // gates
        int j = r & 7, l = (r >> 3) & 63, ks = (r >> 9) & 3, mt = r >> 11;
        int m = mt * 16 + (l & 15);
        int k = ks * 32 + ((l >> 4) << 3) + j;
        int o = m & 63, c = k & 63, half = k >> 6;
        const float* src = (m < 64) ? wf : wg;
        v = src[(((i * 64 + o) * 64 + c) << 1) + half];
    } else {                              // res/skip
        int rr = r - 16384;
        int j = rr & 7, l = (rr >> 3) & 63, ks = (rr >> 9) & 1, mt = rr >> 10;
        int m = mt * 16 + (l & 15);
        int k = ks * 32 + ((l >> 4) << 3) + j;
        v = (m < 64) ? wr[(i * 64 + m) * 64 + k] : wsk[(i * 64 + (m - 64)) * 64 + k];
    }
    out[idx] = f2bf(v);
}

// ---------------------------------------------------------------- init h0 (fp32)
__global__ __launch_bounds__(256) void init_h(
    const float* __restrict__ in, const float* __restrict__ w0,
    const float* __restrict__ b0, float* __restrict__ H)
{
    int idx = blockIdx.x * 256 + threadIdx.x;
    int c = idx >> 16, t = idx & 65535;
    H[idx] = fmaf(w0[c], in[t], b0[c]);
}

// ---------------------------------------------------------------- one layer, MFMA bf16
__global__ __launch_bounds__(256, 3) void layer_mfma(
    const float* __restrict__ Hin, float* __restrict__ Hout,
    float* __restrict__ skip, const ushort_t* __restrict__ PW,
    const float* __restrict__ bf, const float* __restrict__ bg,
    const float* __restrict__ br, const float* __restrict__ bs,
    int d, int tau_start, int accumulate)
{
    __shared__ alignas(16) ushort_t XB[128 * 132 + 128 * 68]; // XB[n][k] pitch132; ZB[n][k] pitch68
    ushort_t* ZB = XB + 128 * 132;
    const int tid = threadIdx.x;
    const int l = tid & 63, w = tid >> 6;
    const int l15 = l & 15, quad = l >> 4;
    const int tau0 = tau_start + (int)blockIdx.x * 128;

    // ---- stage X (transposed, bf16): k<64 = left (tau-d), k>=64 = right
    {
        int n = tid & 127, chalf = tid >> 7;
        #pragma unroll 4
        for (int it = 0; it < 64; ++it) {
            int c = chalf + 2 * it;
            int row = c & 63;
            int tau = tau0 + n - ((c < 64) ? d : 0);
            if (tau > T_TOTAL - 1) tau = T_TOTAL - 1;
            XB[n * 132 + c] = f2bf(Hin[row * T_TOTAL + tau]);
        }
    }
    __syncthreads();

    const int n0w = w * 32;

    // ---- gates GEMM: D(128 x 32cols) = Wfg(128x128) . X(128x32)
    f32x4 acc[8][2];
    #pragma unroll
    for (int mt = 0; mt < 8; ++mt)
        #pragma unroll
        for (int nt = 0; nt < 2; ++nt)
            acc[mt][nt] = (f32x4){0.f, 0.f, 0.f, 0.f};

    #pragma unroll
    for (int ks = 0; ks < 4; ++ks) {
        BF8 bfr[2];
        #pragma unroll
        for (int nt = 0; nt < 2; ++nt) {
            int off = (n0w + nt * 16 + l15) * 132 + ks * 32 + quad * 8;
            bfr[nt].q[0] = *(const unsigned long long*)(XB + off);
            bfr[nt].q[1] = *(const unsigned long long*)(XB + off + 4);
        }
        #pragma unroll
        for (int mt = 0; mt < 8; ++mt) {
            BF8 af;
            af.u4 = *(const uint4v*)(PW + (((mt << 2) + ks) * 64 + l) * 8);
            #pragma unroll
            for (int nt = 0; nt < 2; ++nt)
                acc[mt][nt] = __builtin_amdgcn_mfma_f32_16x16x32_bf16(af.v, bfr[nt].v, acc[mt][nt], 0, 0, 0);
        }
    }

    // ---- z = tanh(f) * sigmoid(g), write transposed bf16 to ZB
    #pragma unroll
    for (int mt = 0; mt < 4; ++mt)
        #pragma unroll
        for (int nt = 0; nt < 2; ++nt)
            #pragma unroll
            for (int r = 0; r < 4; ++r) {
                int frow = mt * 16 + quad * 4 + r;
                float f = acc[mt][nt][r] + bf[frow];
                float g = acc[mt + 4][nt][r] + bg[frow];
                float e2 = __expf(2.0f * f);
                float th = 1.0f - 2.0f / (e2 + 1.0f);
                float sg = 1.0f / (1.0f + __expf(-g));
                ZB[(n0w + nt * 16 + l15) * 68 + frow] = f2bf(th * sg);
            }

    // Barrier: orders the ushort z-stores before the 64-bit ZB reads below.
    // Without it the compiler's alias analysis (TBAA: ushort store vs u64 load)
    // can schedule the ds_read before the ds_write -> uninit LDS -> NaN.
    __syncthreads();

    // ---- res/skip GEMM: D(128 x 32cols) = Wrs(128x64) . Z(64x32)
    f32x4 acc2[8][2];
    #pragma unroll
    for (int mt = 0; mt < 8; ++mt)
        #pragma unroll
        for (int nt = 0; nt < 2; ++nt)
            acc2[mt][nt] = (f32x4){0.f, 0.f, 0.f, 0.f};

    const ushort_t* PRS = PW + 16384;
    #pragma unroll
    for (int ks = 0; ks < 2; ++ks) {
        BF8 bfr[2];
        #pragma unroll
        for (int nt = 0; nt < 2; ++nt) {
            int off = (n0w + nt * 16 + l15) * 68 + ks * 32 + quad * 8;
            bfr[nt].q[0] = *(const unsigned long long*)(ZB + off);
            bfr[nt].q[1] = *(const unsigned long long*)(ZB + off + 4);
        }
        #pragma unroll
        for (int mt = 0; mt < 8; ++mt) {
            BF8 af;
            af.u4 = *(const uint4v*)(PRS + (((mt << 1) + ks) * 64 + l) * 8);
            #pragma unroll
            for (int nt = 0; nt < 2; ++nt)
                acc2[mt][nt] = __builtin_amdgcn_mfma_f32_16x16x32_bf16(af.v, bfr[nt].v, acc2[mt][nt], 0, 0, 0);
        }
    }

    // ---- epilogue: Hout = res + bias + right(fp32); skip += s + bias
    #pragma unroll
    for (int nt = 0; nt < 2; ++nt) {
        int tau = tau0 + n0w + nt * 16 + l15;
        if (tau >= T_TOTAL) continue;
        bool sk = (tau >= OUT_START);
        #pragma unroll
        for (int mt = 0; mt < 4; ++mt)
            #pragma unroll
            for (int r = 0; r < 4; ++r) {
                int mrow = mt * 16 + quad * 4 + r;
                int gidx = mrow * T_TOTAL + tau;
                Hout[gidx] = acc2[mt][nt][r] + br[mrow] + Hin[gidx];
                if (sk) {
                    float sv = acc2[mt + 4][nt][r] + bs[mrow];
                    skip[gidx] = accumulate ? (skip[gidx] + sv) : sv;
                }
            }
    }
}

// ---------------------------------------------------------------- output head (fp32)
__global__ __launch_bounds__(256) void out_kernel(
    const float* __restrict__ skip, const float* __restrict__ alpha,
    const float* __restrict__ W0t, const float* __restrict__ b0,
    const float* __restrict__ W1t, const float* __restrict__ b1,
    float* __restrict__ out)
{
    __shared__ float Y0[64][64];
    __shared__ float Y1[64][64];
    const int tid = threadIdx.x;
    const int col = tid & 63;
    const int row0 = __builtin_amdgcn_readfirstlane((tid >> 6) << 4);
    const int u0 = (int)blockIdx.x * 64;

    for (int idx = tid; idx < 4096; idx += 256) {
        int c = idx >> 6, cc = idx & 63;
        int u = u0 + cc;
        float v = 0.0f;
        if (u < OUT_W) {
            v = skip[c * T_TOTAL + OUT_START + u];
            float a = alpha[c];
            v = v > 0.0f ? v : a * v;
        }
        Y0[c][cc] = v;
    }
    __syncthreads();

    {
        float acc[16];
        #pragma unroll
        for (int r = 0; r < 16; ++r) acc[r] = b0[row0 + r];
        #pragma unroll 2
        for (int c = 0; c < 64; ++c) {
            float x = Y0[c][col];
            const float* __restrict__ wp = W0t + c * 64 + row0;
            #pragma unroll
            for (int r = 0; r < 16; ++r) acc[r] = fmaf(wp[r], x, acc[r]);
        }
        #pragma unroll
        for (int r = 0; r < 16; ++r) {
            float a = alpha[64 + row0 + r];
            float v = acc[r];
            Y1[row0 + r][col] = v > 0.0f ? v : a * v;
        }
    }
    __syncthreads();

    int u = u0 + col;
    #pragma unroll
    for (int p = 0; p < 4; ++p) {
        int o0 = row0 * 4 + p * 16;
        float acc[16];
        #pragma unroll
        for (int r = 0; r < 16; ++r) acc[r] = b1[o0 + r];
        #pragma unroll 2
        for (int c = 0; c < 64; ++c) {
            float x = Y1[c][col];
            const float* __restrict__ wp = W1t + c * 256 + o0;
            #pragma unroll
            for (int r = 0; r < 16; ++r) acc[r] = fmaf(wp[r], x, acc[r]);
        }
        if (u < OUT_W) {
            #pragma unroll
            for (int r = 0; r < 16; ++r) out[(o0 + r) * OUT_W + u] = acc[r];
        }
    }
}

// ---------------------------------------------------------------- launch
extern "C" void kernel_launch(void* const* d_in, const int* in_sizes, int n_in,
                              void* d_out, int out_size, void* d_ws, size_t ws_size,
                              hipStream_t stream)
{
    const float* input  = (const float*)d_in[0];
    const float* w0     = (const float*)d_in[1];
    const float* b0     = (const float*)d_in[2];
    const float* wf     = (const float*)d_in[3];
    const float* bf     = (const float*)d_in[4];
    const float* wg     = (const float*)d_in[5];
    const float* bg     = (const float*)d_in[6];
    const float* wr     = (const float*)d_in[7];
    const float* br     = (const float*)d_in[8];
    const float* wsk    = (const float*)d_in[9];
    const float* bs     = (const float*)d_in[10];
    const float* alpha  = (const float*)d_in[11];
    const float* w_out0 = (const float*)d_in[12];
    const float* b_out0 = (const float*)d_in[13];
    const float* w_out1 = (const float*)d_in[14];
    const float* b_out1 = (const float*)d_in[15];
    float* out = (float*)d_out;

    float* wsbase = (float*)d_ws;
    float* W0t = wsbase + W0T_OFF;
    float* W1t = wsbase + W1T_OFF;
    ushort_t* pbf = (ushort_t*)(wsbase + PBF_OFF_FLOATS);
    float* H[2] = { wsbase + H0_OFF, wsbase + H1_OFF };
    float* skip = wsbase + SKIP_OFF;

    pack_out<<<(PACKF_TOTAL + 255) / 256, 256, 0, stream>>>(w_out0, w_out1, wsbase);
    pack_mfma<<<PBF_TOTAL / 256, 256, 0, stream>>>(wf, wg, wr, wsk, pbf);
    init_h<<<(64 * T_TOTAL) / 256, 256, 0, stream>>>(input, w0, b0, H[0]);

    int C = 0;
    for (int i = 0; i < NLAYERS; ++i) {
        int d = 1 << (i % 10);
        C += d;
        int ncols = T_TOTAL - C;
        int nblk = (ncols + 127) / 128;
        layer_mfma<<<nblk, 256, 0, stream>>>(
            H[i & 1], H[(i + 1) & 1], skip, pbf + i * PBF_PER_LAYER,
            bf + i * 64, bg + i * 64, br + i * 64, bs + i * 64,
            d, C, i > 0 ? 1 : 0);
    }

    out_kernel<<<(OUT_W + 63) / 64, 256, 0, stream>>>(skip, alpha, W0t, b_out0, W1t, b_out1, out);
}

// Round 4
// 663.082 us; speedup vs baseline: 2.5674x; 1.6448x over previous
//
#include <hip/hip_runtime.h>

typedef unsigned short ushort_t;
typedef unsigned long long u64_t;
typedef __attribute__((ext_vector_type(8))) __bf16 bf16x8;
typedef __attribute__((ext_vector_type(4))) float f32x4;
typedef __attribute__((ext_vector_type(4))) unsigned int uint4v;

#define T_TOTAL 65536
#define NLAYERS 20
#define OUT_START 2047
#define OUT_W 63489

// workspace layout (floats) -- identical footprint to R3 (52.4 MB, proven)
#define W0T_OFF 0                       // 4096 floats
#define W1T_OFF 4096                    // 16384 floats
#define PACKF_TOTAL 20480
#define PBF_OFF_FLOATS 20480            // bf16 packs (as ushort*), 491520 ushorts
#define PBF_PER_LAYER 24576             // ushorts: 16384 gates + 8192 rs
#define PBF_TOTAL (NLAYERS * PBF_PER_LAYER)
#define H0_OFF 524288
#define HBUF (64 * T_TOTAL)             // 4194304 floats, layout [tau][ch]
#define H1_OFF (H0_OFF + HBUF)
#define SKIP_OFF (H0_OFF + 2 * HBUF)    // [tau][s] fp32

__device__ __forceinline__ ushort_t f2bf(float x) {
    union { float f; unsigned u; } c; c.f = x;
    unsigned u = c.u + 0x7FFFu + ((c.u >> 16) & 1u);   // RNE
    return (ushort_t)(u >> 16);
}

union BF8 { uint4v u4; bf16x8 v; };

__device__ __forceinline__ bf16x8 cvt8(f32x4 a, f32x4 b) {
    union { unsigned u[4]; bf16x8 v; } r;
    r.u[0] = (unsigned)f2bf(a[0]) | ((unsigned)f2bf(a[1]) << 16);
    r.u[1] = (unsigned)f2bf(a[2]) | ((unsigned)f2bf(a[3]) << 16);
    r.u[2] = (unsigned)f2bf(b[0]) | ((unsigned)f2bf(b[1]) << 16);
    r.u[3] = (unsigned)f2bf(b[2]) | ((unsigned)f2bf(b[3]) << 16);
    return r.v;
}

// ---------------------------------------------------------------- pack out-head (fp32, transposed)
__global__ __launch_bounds__(256) void pack_out(
    const float* __restrict__ w0, const float* __restrict__ w1, float* __restrict__ wp)
{
    int idx = blockIdx.x * 256 + threadIdx.x;
    if (idx >= PACKF_TOTAL) return;
    if (idx < W1T_OFF) {                  // W0t [c][o] 64x64
        int c = idx >> 6, o = idx & 63;
        wp[W0T_OFF + idx] = w0[o * 64 + c];
    } else {                              // W1t [c][o] 64x256
        int rr = idx - W1T_OFF; int c = rr >> 8, o = rr & 255;
        wp[W1T_OFF + rr] = w1[o * 64 + c];
    }
}

// ---------------------------------------------------------------- pack MFMA weights (bf16, A-fragment order)
__global__ __launch_bounds__(256) void pack_mfma(
    const float* __restrict__ wf, const float* __restrict__ wg,
    const float* __restrict__ wr, const float* __restrict__ wsk,
    ushort_t* __restrict__ out)
{
    int idx = blockIdx.x * 256 + threadIdx.x;
    if (idx >= PBF_TOTAL) return;
    int i = idx / PBF_PER_LAYER;
    int r = idx - i * PBF_PER_LAYER;
    float v;
    if (r < 16384) {                      // gates A (128x128 = [f;g] x [left||right])
        int j = r & 7, l = (r >> 3) & 63, ks = (r >> 9) & 3, mt = r >> 11;
        int m = mt * 16 + (l & 15);
        int k = ks * 32 + ((l >> 4) << 3) + j;
        int o = m & 63, c = k & 63, half = k >> 6;
        const float* src = (m < 64) ? wf : wg;
        v = src[(((i * 64 + o) * 64 + c) << 1) + half];
    } else {                              // rs A (128x64 = [r;s] x c)
        int rr = r - 16384;
        int j = rr & 7, l = (rr >> 3) & 63, ks = (rr >> 9) & 1, mt = rr >> 10;
        int m = mt * 16 + (l & 15);
        int k = ks * 32 + ((l >> 4) << 3) + j;
        v = (m < 64) ? wr[(i * 64 + m) * 64 + k] : wsk[(i * 64 + (m - 64)) * 64 + k];
    }
    out[idx] = f2bf(v);
}

// ---------------------------------------------------------------- init h0:  H[tau][ch]
__global__ __launch_bounds__(256) void init_h(
    const float* __restrict__ in, const float* __restrict__ w0,
    const float* __restrict__ b0, float* __restrict__ H)
{
    int idx = blockIdx.x * 256 + threadIdx.x;   // 64*T threads
    int tau = idx >> 6, c = idx & 63;
    H[idx] = fmaf(w0[c], in[tau], b0[c]);
}

// ---------------------------------------------------------------- one layer, MFMA bf16, time-major H
__global__ __launch_bounds__(256) void layer_mfma(
    const float* __restrict__ Hin, float* __restrict__ Hout,
    float* __restrict__ skip, const ushort_t* __restrict__ PW,
    const float* __restrict__ bfb, const float* __restrict__ bgb,
    const float* __restrict__ brb, const float* __restrict__ bsb,
    int d, int tau_start, int accumulate)
{
    __shared__ alignas(16) ushort_t ZB[128 * 72];   // [n_loc][c], pitch 72 (16B aligned, 2-way banks)
    const int tid = threadIdx.x;
    const int l = tid & 63, w = tid >> 6;
    const int l15 = l & 15, quad = l >> 4;
    const int tau0 = tau_start + (int)blockIdx.x * 128;
    int tauN[2]; tauN[0] = tau0 + w * 32 + l15; tauN[1] = tauN[0] + 16;
    int tC[2]; tC[0] = min(tauN[0], T_TOTAL - 1); tC[1] = min(tauN[1], T_TOTAL - 1);

    // per-lane bias vectors at ch = mt*16 + quad*4
    f32x4 bfv[4], bgv[4], brv[4], bsv[4];
    #pragma unroll
    for (int mt = 0; mt < 4; ++mt) {
        int chb = mt * 16 + quad * 4;
        bfv[mt] = *(const f32x4*)(bfb + chb);
        bgv[mt] = *(const f32x4*)(bgb + chb);
        brv[mt] = *(const f32x4*)(brb + chb);
        bsv[mt] = *(const f32x4*)(bsb + chb);
    }

    // ---- gates GEMM: D(128 x 32cols) = Wfg(128x128) . X(128x32); B straight from global
    f32x4 acc[8][2];
    #pragma unroll
    for (int mt = 0; mt < 8; ++mt) { acc[mt][0] = (f32x4){0,0,0,0}; acc[mt][1] = (f32x4){0,0,0,0}; }

    #pragma unroll
    for (int ks = 0; ks < 4; ++ks) {
        const int dd = (ks < 2) ? d : 0;
        const int chb = (ks & 1) * 32 + quad * 8;
        bf16x8 bfr[2];
        #pragma unroll
        for (int nt = 0; nt < 2; ++nt) {
            const float* p = Hin + (tC[nt] - dd) * 64 + chb;
            f32x4 x0 = *(const f32x4*)p;
            f32x4 x1 = *(const f32x4*)(p + 4);
            bfr[nt] = cvt8(x0, x1);
        }
        #pragma unroll
        for (int mt = 0; mt < 8; ++mt) {
            BF8 af; af.u4 = *(const uint4v*)(PW + (((mt << 2) + ks) * 64 + l) * 8);
            acc[mt][0] = __builtin_amdgcn_mfma_f32_16x16x32_bf16(af.v, bfr[0], acc[mt][0], 0, 0, 0);
            acc[mt][1] = __builtin_amdgcn_mfma_f32_16x16x32_bf16(af.v, bfr[1], acc[mt][1], 0, 0, 0);
        }
    }

    // ---- z = tanh(f)*sigmoid(g) -> ZB (u64 packed stores)
    #pragma unroll
    for (int nt = 0; nt < 2; ++nt) {
        int nloc = w * 32 + nt * 16 + l15;
        #pragma unroll
        for (int mt = 0; mt < 4; ++mt) {
            u64_t pk = 0;
            #pragma unroll
            for (int r = 0; r < 4; ++r) {
                float f = acc[mt][nt][r] + bfv[mt][r];
                float g = acc[mt + 4][nt][r] + bgv[mt][r];
                float e2 = __expf(2.0f * f);
                float th = 1.0f - 2.0f / (e2 + 1.0f);
                float sg = 1.0f / (1.0f + __expf(-g));
                pk |= (u64_t)f2bf(th * sg) << (r * 16);
            }
            *(u64_t*)(ZB + nloc * 72 + mt * 16 + quad * 4) = pk;
        }
    }
    __syncthreads();   // orders u16/u64 ZB stores before 128-bit ZB reads (R2 lesson)

    // ---- res/skip GEMM: D(128 x 32cols) = Wrs(128x64) . Z(64x32)
    f32x4 acc2[8][2];
    #pragma unroll
    for (int mt = 0; mt < 8; ++mt) { acc2[mt][0] = (f32x4){0,0,0,0}; acc2[mt][1] = (f32x4){0,0,0,0}; }

    const ushort_t* PRS = PW + 16384;
    #pragma unroll
    for (int ks = 0; ks < 2; ++ks) {
        bf16x8 bfr[2];
        #pragma unroll
        for (int nt = 0; nt < 2; ++nt) {
            BF8 t; t.u4 = *(const uint4v*)(ZB + (w * 32 + nt * 16 + l15) * 72 + ks * 32 + quad * 8);
            bfr[nt] = t.v;
        }
        #pragma unroll
        for (int mt = 0; mt < 8; ++mt) {
            BF8 af; af.u4 = *(const uint4v*)(PRS + (((mt << 1) + ks) * 64 + l) * 8);
            acc2[mt][0] = __builtin_amdgcn_mfma_f32_16x16x32_bf16(af.v, bfr[0], acc2[mt][0], 0, 0, 0);
            acc2[mt][1] = __builtin_amdgcn_mfma_f32_16x16x32_bf16(af.v, bfr[1], acc2[mt][1], 0, 0, 0);
        }
    }

    // ---- epilogue: float4 stores, time-major
    #pragma unroll
    for (int nt = 0; nt < 2; ++nt) {
        int tau = tauN[nt];
        if (tau >= T_TOTAL) continue;
        const float* hb = Hin + tau * 64;
        float* ho = Hout + tau * 64;
        float* sp = skip + tau * 64;
        bool sk = (tau >= OUT_START);
        #pragma unroll
        for (int mt = 0; mt < 4; ++mt) {
            int chb = mt * 16 + quad * 4;
            f32x4 h = *(const f32x4*)(hb + chb);
            f32x4 o;
            #pragma unroll
            for (int r = 0; r < 4; ++r) o[r] = acc2[mt][nt][r] + brv[mt][r] + h[r];
            *(f32x4*)(ho + chb) = o;
            if (sk) {
                f32x4 s;
                if (accumulate) {
                    s = *(const f32x4*)(sp + chb);
                    #pragma unroll
                    for (int r = 0; r < 4; ++r) s[r] += acc2[mt + 4][nt][r] + bsv[mt][r];
                } else {
                    #pragma unroll
                    for (int r = 0; r < 4; ++r) s[r] = acc2[mt + 4][nt][r] + bsv[mt][r];
                }
                *(f32x4*)(sp + chb) = s;
            }
        }
    }
}

// ---------------------------------------------------------------- output head (fp32), skip is [tau][s]
__global__ __launch_bounds__(256) void out_kernel(
    const float* __restrict__ skip, const float* __restrict__ alpha,
    const float* __restrict__ W0t, const float* __restrict__ b0,
    const float* __restrict__ W1t, const float* __restrict__ b1,
    float* __restrict__ out)
{
    __shared__ float Y0[64][64];
    __shared__ float Y1[64][64];
    const int tid = threadIdx.x;
    const int col = tid & 63;
    const int row0 = __builtin_amdgcn_readfirstlane((tid >> 6) << 4);
    const int u0 = (int)blockIdx.x * 64;

    for (int idx = tid; idx < 1024; idx += 256) {
        int cq = idx & 15, ul = idx >> 4;
        int c0 = cq * 4;
        int u = u0 + ul;
        f32x4 v = (f32x4){0, 0, 0, 0};
        if (u < OUT_W) v = *(const f32x4*)(skip + (OUT_START + u) * 64 + c0);
        #pragma unroll
        for (int i = 0; i < 4; ++i) {
            float a = alpha[c0 + i];
            float x = v[i];
            Y0[c0 + i][ul] = x > 0.0f ? x : a * x;
        }
    }
    __syncthreads();

    {
        float acc[16];
        #pragma unroll
        for (int r = 0; r < 16; ++r) acc[r] = b0[row0 + r];
        #pragma unroll 2
        for (int c = 0; c < 64; ++c) {
            float x = Y0[c][col];
            const float* __restrict__ wp = W0t + c * 64 + row0;
            #pragma unroll
            for (int r = 0; r < 16; ++r) acc[r] = fmaf(wp[r], x, acc[r]);
        }
        #pragma unroll
        for (int r = 0; r < 16; ++r) {
            float a = alpha[64 + row0 + r];
            float v = acc[r];
            Y1[row0 + r][col] = v > 0.0f ? v : a * v;
        }
    }
    __syncthreads();

    int u = u0 + col;
    #pragma unroll
    for (int p = 0; p < 4; ++p) {
        int o0 = row0 * 4 + p * 16;
        float acc[16];
        #pragma unroll
        for (int r = 0; r < 16; ++r) acc[r] = b1[o0 + r];
        #pragma unroll 2
        for (int c = 0; c < 64; ++c) {
            float x = Y1[c][col];
            const float* __restrict__ wp = W1t + c * 256 + o0;
            #pragma unroll
            for (int r = 0; r < 16; ++r) acc[r] = fmaf(wp[r], x, acc[r]);
        }
        if (u < OUT_W) {
            #pragma unroll
            for (int r = 0; r < 16; ++r) out[(o0 + r) * OUT_W + u] = acc[r];
        }
    }
}

// ---------------------------------------------------------------- launch
extern "C" void kernel_launch(void* const* d_in, const int* in_sizes, int n_in,
                              void* d_out, int out_size, void* d_ws, size_t ws_size,
                              hipStream_t stream)
{
    const float* input  = (const float*)d_in[0];
    const float* w0     = (const float*)d_in[1];
    const float* b0     = (const float*)d_in[2];
    const float* wf     = (const float*)d_in[3];
    const float* bf     = (const float*)d_in[4];
    const float* wg     = (const float*)d_in[5];
    const float* bg     = (const float*)d_in[6];
    const float* wr     = (const float*)d_in[7];
    const float* br     = (const float*)d_in[8];
    const float* wsk    = (const float*)d_in[9];
    const float* bs     = (const float*)d_in[10];
    const float* alpha  = (const float*)d_in[11];
    const float* w_out0 = (const float*)d_in[12];
    const float* b_out0 = (const float*)d_in[13];
    const float* w_out1 = (const float*)d_in[14];
    const float* b_out1 = (const float*)d_in[15];
    float* out = (float*)d_out;

    float* wsbase = (float*)d_ws;
    float* W0t = wsbase + W0T_OFF;
    float* W1t = wsbase + W1T_OFF;
    ushort_t* pbf = (ushort_t*)(wsbase + PBF_OFF_FLOATS);
    float* H[2] = { wsbase + H0_OFF, wsbase + H1_OFF };
    float* skip = wsbase + SKIP_OFF;

    pack_out<<<(PACKF_TOTAL + 255) / 256, 256, 0, stream>>>(w_out0, w_out1, wsbase);
    pack_mfma<<<PBF_TOTAL / 256, 256, 0, stream>>>(wf, wg, wr, wsk, pbf);
    init_h<<<(64 * T_TOTAL) / 256, 256, 0, stream>>>(input, w0, b0, H[0]);

    int C = 0;
    for (int i = 0; i < NLAYERS; ++i) {
        int d = 1 << (i % 10);
        C += d;
        int ncols = T_TOTAL - C;
        int nblk = (ncols + 127) / 128;
        layer_mfma<<<nblk, 256, 0, stream>>>(
            H[i & 1], H[(i + 1) & 1], skip, pbf + i * PBF_PER_LAYER,
            bf + i * 64, bg + i * 64, br + i * 64, bs + i * 64,
            d, C, i > 0 ? 1 : 0);
    }

    out_kernel<<<(OUT_W + 63) / 64, 256, 0, stream>>>(skip, alpha, W0t, b_out0, W1t, b_out1, out);
}

// Round 5
// 631.873 us; speedup vs baseline: 2.6942x; 1.0494x over previous
//
#include <hip/hip_runtime.h>

typedef unsigned short ushort_t;
typedef unsigned long long u64_t;
typedef __attribute__((ext_vector_type(8))) __bf16 bf16x8;
typedef __attribute__((ext_vector_type(4))) float f32x4;
typedef __attribute__((ext_vector_type(4))) unsigned int uint4v;

#define T_TOTAL 65536
#define NLAYERS 20
#define OUT_START 2047
#define OUT_W 63489

// workspace layout
// pbf (ushort) at float-offset 0: 20 layers * 24576 + W0 4096 + W1 16384 = 512000 ushorts
#define PBF_PER_LAYER 24576
#define PBF_LAYERS (NLAYERS * PBF_PER_LAYER)        // 491520
#define PBF_TOTAL (PBF_LAYERS + 4096 + 16384)       // 512000 ushorts = 256000 floats
#define H0_OFF 524288
#define HBUF (64 * T_TOTAL)                          // [tau][ch] fp32
#define H1_OFF (H0_OFF + HBUF)
#define SKIP_OFF (H0_OFF + 2 * HBUF)                 // [tau][s] fp32

__device__ __forceinline__ ushort_t f2bf(float x) {
    union { float f; unsigned u; } c; c.f = x;
    unsigned u = c.u + 0x7FFFu + ((c.u >> 16) & 1u);   // RNE
    return (ushort_t)(u >> 16);
}

union BF8 { uint4v u4; bf16x8 v; };

__device__ __forceinline__ bf16x8 cvt8(f32x4 a, f32x4 b) {
    union { unsigned u[4]; bf16x8 v; } r;
    r.u[0] = (unsigned)f2bf(a[0]) | ((unsigned)f2bf(a[1]) << 16);
    r.u[1] = (unsigned)f2bf(a[2]) | ((unsigned)f2bf(a[3]) << 16);
    r.u[2] = (unsigned)f2bf(b[0]) | ((unsigned)f2bf(b[1]) << 16);
    r.u[3] = (unsigned)f2bf(b[2]) | ((unsigned)f2bf(b[3]) << 16);
    return r.v;
}

// ---------------------------------------------------------------- pack ALL MFMA weights (bf16, A-fragment order)
__global__ __launch_bounds__(256) void pack_mfma(
    const float* __restrict__ wf, const float* __restrict__ wg,
    const float* __restrict__ wr, const float* __restrict__ wsk,
    const float* __restrict__ w0h, const float* __restrict__ w1h,
    ushort_t* __restrict__ out)
{
    int idx = blockIdx.x * 256 + threadIdx.x;
    if (idx >= PBF_TOTAL) return;
    float v;
    if (idx < PBF_LAYERS) {
        int i = idx / PBF_PER_LAYER;
        int r = idx - i * PBF_PER_LAYER;
        if (r < 16384) {                  // gates A (128x128 = [f;g] x [left||right])
            int j = r & 7, l = (r >> 3) & 63, ks = (r >> 9) & 3, mt = r >> 11;
            int m = mt * 16 + (l & 15);
            int k = ks * 32 + ((l >> 4) << 3) + j;
            int o = m & 63, c = k & 63, half = k >> 6;
            const float* src = (m < 64) ? wf : wg;
            v = src[(((i * 64 + o) * 64 + c) << 1) + half];
        } else {                          // rs A (128x64 = [r;s] x c)
            int rr = r - 16384;
            int j = rr & 7, l = (rr >> 3) & 63, ks = (rr >> 9) & 1, mt = rr >> 10;
            int m = mt * 16 + (l & 15);
            int k = ks * 32 + ((l >> 4) << 3) + j;
            v = (m < 64) ? wr[(i * 64 + m) * 64 + k] : wsk[(i * 64 + (m - 64)) * 64 + k];
        }
    } else if (idx < PBF_LAYERS + 4096) { // W0 head (64x64)
        int rr = idx - PBF_LAYERS;
        int j = rr & 7, l = (rr >> 3) & 63, ks = (rr >> 9) & 1, mt = rr >> 10;
        int m = mt * 16 + (l & 15);
        int k = ks * 32 + ((l >> 4) << 3) + j;
        v = w0h[m * 64 + k];
    } else {                              // W1 head (256x64)
        int rr = idx - PBF_LAYERS - 4096;
        int j = rr & 7, l = (rr >> 3) & 63, ks = (rr >> 9) & 1, mt = rr >> 10;
        int m = mt * 16 + (l & 15);
        int k = ks * 32 + ((l >> 4) << 3) + j;
        v = w1h[m * 64 + k];
    }
    out[idx] = f2bf(v);
}

// ---------------------------------------------------------------- init h0:  H[tau][ch]
__global__ __launch_bounds__(256) void init_h(
    const float* __restrict__ in, const float* __restrict__ w0,
    const float* __restrict__ b0, float* __restrict__ H)
{
    int idx = blockIdx.x * 256 + threadIdx.x;
    int tau = idx >> 6, c = idx & 63;
    H[idx] = fmaf(w0[c], in[tau], b0[c]);
}

// ---------------------------------------------------------------- one layer, MFMA bf16, time-major H
__global__ __launch_bounds__(256) void layer_mfma(
    const float* __restrict__ Hin, float* __restrict__ Hout,
    float* __restrict__ skip, const ushort_t* __restrict__ PW,
    const float* __restrict__ bfb, const float* __restrict__ bgb,
    const float* __restrict__ brb, const float* __restrict__ bsb,
    int d, int tau_start, int accumulate)
{
    __shared__ alignas(16) ushort_t ZB[128 * 72];
    const int tid = threadIdx.x;
    const int l = tid & 63, w = tid >> 6;
    const int l15 = l & 15, quad = l >> 4;
    const int tau0 = tau_start + (int)blockIdx.x * 128;
    int tauN[2]; tauN[0] = tau0 + w * 32 + l15; tauN[1] = tauN[0] + 16;
    int tC[2]; tC[0] = min(tauN[0], T_TOTAL - 1); tC[1] = min(tauN[1], T_TOTAL - 1);

    // ---- gates GEMM, biases folded into accumulator init (saves 64 live VGPRs)
    f32x4 acc[8][2];
    #pragma unroll
    for (int mt = 0; mt < 4; ++mt) {
        f32x4 bfv = *(const f32x4*)(bfb + mt * 16 + quad * 4);
        f32x4 bgv = *(const f32x4*)(bgb + mt * 16 + quad * 4);
        acc[mt][0] = bfv; acc[mt][1] = bfv;
        acc[mt + 4][0] = bgv; acc[mt + 4][1] = bgv;
    }

    #pragma unroll
    for (int ks = 0; ks < 4; ++ks) {
        const int dd = (ks < 2) ? d : 0;
        const int chb = (ks & 1) * 32 + quad * 8;
        bf16x8 bfr[2];
        #pragma unroll
        for (int nt = 0; nt < 2; ++nt) {
            const float* p = Hin + (tC[nt] - dd) * 64 + chb;
            f32x4 x0 = *(const f32x4*)p;
            f32x4 x1 = *(const f32x4*)(p + 4);
            bfr[nt] = cvt8(x0, x1);
        }
        #pragma unroll
        for (int mt = 0; mt < 8; ++mt) {
            BF8 af; af.u4 = *(const uint4v*)(PW + (((mt << 2) + ks) * 64 + l) * 8);
            acc[mt][0] = __builtin_amdgcn_mfma_f32_16x16x32_bf16(af.v, bfr[0], acc[mt][0], 0, 0, 0);
            acc[mt][1] = __builtin_amdgcn_mfma_f32_16x16x32_bf16(af.v, bfr[1], acc[mt][1], 0, 0, 0);
        }
    }

    // ---- z = tanh(f)*sigmoid(g) -> ZB
    #pragma unroll
    for (int nt = 0; nt < 2; ++nt) {
        int nloc = w * 32 + nt * 16 + l15;
        #pragma unroll
        for (int mt = 0; mt < 4; ++mt) {
            u64_t pk = 0;
            #pragma unroll
            for (int r = 0; r < 4; ++r) {
                float f = acc[mt][nt][r];
                float g = acc[mt + 4][nt][r];
                float e2 = __expf(2.0f * f);
                float th = 1.0f - 2.0f / (e2 + 1.0f);
                float sg = 1.0f / (1.0f + __expf(-g));
                pk |= (u64_t)f2bf(th * sg) << (r * 16);
            }
            *(u64_t*)(ZB + nloc * 72 + mt * 16 + quad * 4) = pk;
        }
    }
    __syncthreads();   // orders ZB stores before 128-bit ZB reads (R2 TBAA lesson)

    // ---- res/skip GEMM, biases in acc init
    f32x4 acc2[8][2];
    #pragma unroll
    for (int mt = 0; mt < 4; ++mt) {
        f32x4 brv = *(const f32x4*)(brb + mt * 16 + quad * 4);
        f32x4 bsv = *(const f32x4*)(bsb + mt * 16 + quad * 4);
        acc2[mt][0] = brv; acc2[mt][1] = brv;
        acc2[mt + 4][0] = bsv; acc2[mt + 4][1] = bsv;
    }

    const ushort_t* PRS = PW + 16384;
    #pragma unroll
    for (int ks = 0; ks < 2; ++ks) {
        bf16x8 bfr[2];
        #pragma unroll
        for (int nt = 0; nt < 2; ++nt) {
            BF8 t; t.u4 = *(const uint4v*)(ZB + (w * 32 + nt * 16 + l15) * 72 + ks * 32 + quad * 8);
            bfr[nt] = t.v;
        }
        #pragma unroll
        for (int mt = 0; mt < 8; ++mt) {
            BF8 af; af.u4 = *(const uint4v*)(PRS + (((mt << 1) + ks) * 64 + l) * 8);
            acc2[mt][0] = __builtin_amdgcn_mfma_f32_16x16x32_bf16(af.v, bfr[0], acc2[mt][0], 0, 0, 0);
            acc2[mt][1] = __builtin_amdgcn_mfma_f32_16x16x32_bf16(af.v, bfr[1], acc2[mt][1], 0, 0, 0);
        }
    }

    // ---- epilogue
    #pragma unroll
    for (int nt = 0; nt < 2; ++nt) {
        int tau = tauN[nt];
        if (tau >= T_TOTAL) continue;
        const float* hb = Hin + tau * 64;
        float* ho = Hout + tau * 64;
        float* sp = skip + tau * 64;
        bool sk = (tau >= OUT_START);
        #pragma unroll
        for (int mt = 0; mt < 4; ++mt) {
            int chb = mt * 16 + quad * 4;
            f32x4 h = *(const f32x4*)(hb + chb);
            f32x4 o;
            #pragma unroll
            for (int r = 0; r < 4; ++r) o[r] = acc2[mt][nt][r] + h[r];
            *(f32x4*)(ho + chb) = o;
            if (sk) {
                f32x4 s;
                if (accumulate) {
                    s = *(const f32x4*)(sp + chb);
                    #pragma unroll
                    for (int r = 0; r < 4; ++r) s[r] += acc2[mt + 4][nt][r];
                } else {
                    #pragma unroll
                    for (int r = 0; r < 4; ++r) s[r] = acc2[mt + 4][nt][r];
                }
                *(f32x4*)(sp + chb) = s;
            }
        }
    }
}

// ---------------------------------------------------------------- output head, MFMA bf16
__global__ __launch_bounds__(256) void out_head(
    const float* __restrict__ skip, const float* __restrict__ alpha,
    const ushort_t* __restrict__ PW0, const ushort_t* __restrict__ PW1,
    const float* __restrict__ b0, const float* __restrict__ b1,
    float* __restrict__ out)
{
    __shared__ alignas(16) ushort_t YB[64 * 72];
    const int tid = threadIdx.x;
    const int l = tid & 63, w = tid >> 6;
    const int l15 = l & 15, quad = l >> 4;
    const int u0 = (int)blockIdx.x * 64;

    // ---- stage Y0 = lrelu(skip) as bf16 B-fragments [u_loc][c]
    for (int idx = tid; idx < 1024; idx += 256) {
        int uloc = idx >> 4, c0 = (idx & 15) * 4;
        int u = u0 + uloc;
        f32x4 v = (f32x4){0, 0, 0, 0};
        if (u < OUT_W) v = *(const f32x4*)(skip + (OUT_START + u) * 64 + c0);
        f32x4 a = *(const f32x4*)(alpha + c0);
        u64_t pk = 0;
        #pragma unroll
        for (int i = 0; i < 4; ++i) {
            float x = v[i] > 0.0f ? v[i] : a[i] * v[i];
            pk |= (u64_t)f2bf(x) << (i * 16);
        }
        *(u64_t*)(YB + uloc * 72 + c0) = pk;
    }
    __syncthreads();

    const int nloc = w * 16 + l15;

    // ---- W0 GEMM (64x64), bias in acc init
    f32x4 acc0[4];
    #pragma unroll
    for (int mt = 0; mt < 4; ++mt) acc0[mt] = *(const f32x4*)(b0 + mt * 16 + quad * 4);
    #pragma unroll
    for (int ks = 0; ks < 2; ++ks) {
        BF8 t; t.u4 = *(const uint4v*)(YB + nloc * 72 + ks * 32 + quad * 8);
        #pragma unroll
        for (int mt = 0; mt < 4; ++mt) {
            BF8 af; af.u4 = *(const uint4v*)(PW0 + (((mt << 1) + ks) * 64 + l) * 8);
            acc0[mt] = __builtin_amdgcn_mfma_f32_16x16x32_bf16(af.v, t.v, acc0[mt], 0, 0, 0);
        }
    }
    __syncthreads();   // all W0 reads of YB done before overwrite

    // ---- lrelu(alpha1) -> X1 back into YB (each wave touches only its own 16 rows)
    #pragma unroll
    for (int mt = 0; mt < 4; ++mt) {
        f32x4 a = *(const f32x4*)(alpha + 64 + mt * 16 + quad * 4);
        u64_t pk = 0;
        #pragma unroll
        for (int r = 0; r < 4; ++r) {
            float x = acc0[mt][r];
            x = x > 0.0f ? x : a[r] * x;
            pk |= (u64_t)f2bf(x) << (r * 16);
        }
        *(u64_t*)(YB + nloc * 72 + mt * 16 + quad * 4) = pk;
    }
    __syncthreads();

    // ---- W1 GEMM (256x64), bias in acc init
    f32x4 acc1[16];
    #pragma unroll
    for (int mt = 0; mt < 16; ++mt) acc1[mt] = *(const f32x4*)(b1 + mt * 16 + quad * 4);
    #pragma unroll
    for (int ks = 0; ks < 2; ++ks) {
        BF8 t; t.u4 = *(const uint4v*)(YB + nloc * 72 + ks * 32 + quad * 8);
        #pragma unroll
        for (int mt = 0; mt < 16; ++mt) {
            BF8 af; af.u4 = *(const uint4v*)(PW1 + (((mt << 1) + ks) * 64 + l) * 8);
            acc1[mt] = __builtin_amdgcn_mfma_f32_16x16x32_bf16(af.v, t.v, acc1[mt], 0, 0, 0);
        }
    }

    int u = u0 + nloc;
    if (u < OUT_W) {
        #pragma unroll
        for (int mt = 0; mt < 16; ++mt)
            #pragma unroll
            for (int r = 0; r < 4; ++r)
                out[(mt * 16 + quad * 4 + r) * OUT_W + u] = acc1[mt][r];
    }
}

// ---------------------------------------------------------------- launch
extern "C" void kernel_launch(void* const* d_in, const int* in_sizes, int n_in,
                              void* d_out, int out_size, void* d_ws, size_t ws_size,
                              hipStream_t stream)
{
    const float* input  = (const float*)d_in[0];
    const float* w0     = (const float*)d_in[1];
    const float* b0     = (const float*)d_in[2];
    const float* wf     = (const float*)d_in[3];
    const float* bf     = (const float*)d_in[4];
    const float* wg     = (const float*)d_in[5];
    const float* bg     = (const float*)d_in[6];
    const float* wr     = (const float*)d_in[7];
    const float* br     = (const float*)d_in[8];
    const float* wsk    = (const float*)d_in[9];
    const float* bs     = (const float*)d_in[10];
    const float* alpha  = (const float*)d_in[11];
    const float* w_out0 = (const float*)d_in[12];
    const float* b_out0 = (const float*)d_in[13];
    const float* w_out1 = (const float*)d_in[14];
    const float* b_out1 = (const float*)d_in[15];
    float* out = (float*)d_out;

    float* wsbase = (float*)d_ws;
    ushort_t* pbf = (ushort_t*)wsbase;
    ushort_t* PW0 = pbf + PBF_LAYERS;
    ushort_t* PW1 = PW0 + 4096;
    float* H[2] = { wsbase + H0_OFF, wsbase + H1_OFF };
    float* skip = wsbase + SKIP_OFF;

    pack_mfma<<<PBF_TOTAL / 256, 256, 0, stream>>>(wf, wg, wr, wsk, w_out0, w_out1, pbf);
    init_h<<<(64 * T_TOTAL) / 256, 256, 0, stream>>>(input, w0, b0, H[0]);

    int C = 0;
    for (int i = 0; i < NLAYERS; ++i) {
        int d = 1 << (i % 10);
        C += d;
        int ncols = T_TOTAL - C;
        int nblk = (ncols + 127) / 128;
        layer_mfma<<<nblk, 256, 0, stream>>>(
            H[i & 1], H[(i + 1) & 1], skip, pbf + i * PBF_PER_LAYER,
            bf + i * 64, bg + i * 64, br + i * 64, bs + i * 64,
            d, C, i > 0 ? 1 : 0);
    }

    out_head<<<(OUT_W + 63) / 64, 256, 0, stream>>>(skip, alpha, PW0, PW1, b_out0, b_out1, out);
}